// Round 1
// baseline (562.476 us; speedup 1.0000x reference)
//
#include <hip/hip_runtime.h>
#include <hip/hip_bf16.h>
#include <math.h>

// Problem constants (B=512, D=768, H=256)
#define B 512
#define D 768
#define H 256
#define NN 128          // n = B/4
#define MM 256          // m = B/2
#define P_PAIRS 57280   // sum_{i=0}^{127} (511 - i)

// ---------------- Kernel 1: row L2 normalize ----------------
__global__ __launch_bounds__(256) void k_normalize(const float* __restrict__ emb,
                                                   float* __restrict__ z) {
    int i = blockIdx.x;                  // 0..511
    const float* row = emb + i * D;
    float ss = 0.f;
    for (int d = threadIdx.x; d < D; d += 256) {
        float v = row[d];
        ss += v * v;
    }
    __shared__ float red[256];
    red[threadIdx.x] = ss;
    __syncthreads();
    for (int s = 128; s > 0; s >>= 1) {
        if (threadIdx.x < s) red[threadIdx.x] += red[threadIdx.x + s];
        __syncthreads();
    }
    float inv = 1.0f / fmaxf(sqrtf(red[0]), 1e-12f);
    for (int d = threadIdx.x; d < D; d += 256) {
        z[i * D + d] = row[d] * inv;
    }
}

// ---------------- Kernel 2: contrastive stats per row i<128 ----------------
// logden[i] = log( sum_{k != i} exp(2*dot(z_i, z_k)) )
// slog[i]   = sum_{i < k < 128} 2*dot(z_i, z_k)
__global__ __launch_bounds__(256) void k_cstats(const float* __restrict__ z,
                                                float* __restrict__ logden,
                                                float* __restrict__ slog) {
    __shared__ float zi[2][D];           // 6 KB
    int i0 = blockIdx.x * 2;             // 64 blocks -> i in [0,128)
    for (int idx = threadIdx.x; idx < 2 * D; idx += 256)
        zi[idx / D][idx % D] = z[i0 * D + idx];
    __syncthreads();

    float den[2] = {0.f, 0.f}, sl[2] = {0.f, 0.f};
    for (int k = threadIdx.x; k < B; k += 256) {
        const float4* zk = (const float4*)(z + k * D);
        float dot0 = 0.f, dot1 = 0.f;
        #pragma unroll 4
        for (int d4 = 0; d4 < D / 4; d4++) {
            float4 v = zk[d4];
            float4 a = *(const float4*)&zi[0][d4 * 4];
            float4 b = *(const float4*)&zi[1][d4 * 4];
            dot0 += v.x * a.x + v.y * a.y + v.z * a.z + v.w * a.w;
            dot1 += v.x * b.x + v.y * b.y + v.z * b.z + v.w * b.w;
        }
        float dots[2] = {dot0, dot1};
        #pragma unroll
        for (int r = 0; r < 2; r++) {
            int i = i0 + r;
            if (k != i) den[r] += expf(2.f * dots[r]);
            if (k > i && k < NN) sl[r] += 2.f * dots[r];
        }
    }

    __shared__ float red[256];
    #pragma unroll
    for (int r = 0; r < 2; r++) {
        red[threadIdx.x] = den[r];
        __syncthreads();
        for (int s = 128; s > 0; s >>= 1) {
            if (threadIdx.x < s) red[threadIdx.x] += red[threadIdx.x + s];
            __syncthreads();
        }
        if (threadIdx.x == 0) logden[i0 + r] = logf(red[0]);
        __syncthreads();
        red[threadIdx.x] = sl[r];
        __syncthreads();
        for (int s = 128; s > 0; s >>= 1) {
            if (threadIdx.x < s) red[threadIdx.x] += red[threadIdx.x + s];
            __syncthreads();
        }
        if (threadIdx.x == 0) slog[i0 + r] = red[0];
        __syncthreads();
    }
}

// ---------------- Kernel 3: U = z @ W1[:, :D].T ; V = z @ W1[:, D:].T ----------------
__global__ __launch_bounds__(256) void k_uv(const float* __restrict__ z,
                                            const float* __restrict__ W1,
                                            float* __restrict__ U,
                                            float* __restrict__ V) {
    __shared__ float zi[4][D];           // 12 KB
    int i0 = blockIdx.x * 4;             // 128 blocks -> rows 0..511
    for (int idx = threadIdx.x; idx < 4 * D; idx += 256)
        zi[idx / D][idx % D] = z[i0 * D + idx];
    __syncthreads();

    int t = threadIdx.x;                 // output index h = t (0..255)
    const float4* wa = (const float4*)(W1 + t * (2 * D));
    const float4* wb = (const float4*)(W1 + t * (2 * D) + D);
    float aU[4] = {0.f, 0.f, 0.f, 0.f};
    float aV[4] = {0.f, 0.f, 0.f, 0.f};
    for (int d4 = 0; d4 < D / 4; d4++) {
        float4 A = wa[d4], Bv = wb[d4];
        #pragma unroll
        for (int r = 0; r < 4; r++) {
            float4 zz = *(const float4*)&zi[r][d4 * 4];
            aU[r] += zz.x * A.x + zz.y * A.y + zz.z * A.z + zz.w * A.w;
            aV[r] += zz.x * Bv.x + zz.y * Bv.y + zz.z * Bv.z + zz.w * Bv.w;
        }
    }
    #pragma unroll
    for (int r = 0; r < 4; r++) {
        U[(i0 + r) * H + t] = aU[r];
        V[(i0 + r) * H + t] = aV[r];
    }
}

// ---------------- Kernel 4: pair MLP (layer2+layer3+BCE), fused ----------------
// Grid: (16 j-tiles of 32, 128 i). Block: 256 threads.
// Thread layout for compute: wave w = tid/64 owns pairs 8w..8w+7;
// lane og = tid%64 owns outputs 4og..4og+3.
__global__ __launch_bounds__(256) void k_pairs(const float* __restrict__ U,
                                               const float* __restrict__ V,
                                               const float* __restrict__ W2,
                                               const float* __restrict__ b1,
                                               const float* __restrict__ b2,
                                               const float* __restrict__ W3,
                                               const float* __restrict__ b3,
                                               float* __restrict__ bce_sum) {
    int i = blockIdx.y;                  // 0..127
    int j0 = blockIdx.x * 32;            // tile base in j
    if (j0 + 31 <= i) return;            // whole tile has j <= i -> nothing to do

    __shared__ float h1[32][H];          // 32 KB
    int tid = threadIdx.x;

    // Stage h1[t][h] = relu(U[i][h] + V[j][h] + b1[h]); h = tid
    float u = U[i * H + tid];
    float bb1 = b1[tid];
    for (int t = 0; t < 32; t++) {
        int j = j0 + t;
        int jc = (j < B) ? j : (B - 1);  // clamp for safe read; masked later
        float v = V[jc * H + tid];
        h1[t][tid] = fmaxf(u + v + bb1, 0.f);
    }
    __syncthreads();

    int og = tid & 63;
    int w = tid >> 6;
    float acc[4][8];
    #pragma unroll
    for (int r = 0; r < 4; r++)
        #pragma unroll
        for (int p = 0; p < 8; p++) acc[r][p] = 0.f;

    const float* w2base = W2 + (4 * og) * H;
    for (int k4 = 0; k4 < H; k4 += 4) {
        float4 wv0 = *(const float4*)(w2base + 0 * H + k4);
        float4 wv1 = *(const float4*)(w2base + 1 * H + k4);
        float4 wv2 = *(const float4*)(w2base + 2 * H + k4);
        float4 wv3 = *(const float4*)(w2base + 3 * H + k4);
        #pragma unroll
        for (int p = 0; p < 8; p++) {
            float4 a = *(const float4*)(&h1[8 * w + p][k4]);  // wave-broadcast
            acc[0][p] += a.x * wv0.x + a.y * wv0.y + a.z * wv0.z + a.w * wv0.w;
            acc[1][p] += a.x * wv1.x + a.y * wv1.y + a.z * wv1.z + a.w * wv1.w;
            acc[2][p] += a.x * wv2.x + a.y * wv2.y + a.z * wv2.z + a.w * wv2.w;
            acc[3][p] += a.x * wv3.x + a.y * wv3.y + a.z * wv3.z + a.w * wv3.w;
        }
    }

    // Epilogue: h2 = relu(acc + b2), partial logit = sum_o h2[o]*W3[o]
    float bb2[4], w3v[4];
    #pragma unroll
    for (int r = 0; r < 4; r++) {
        bb2[r] = b2[4 * og + r];
        w3v[r] = W3[4 * og + r];
    }
    float b3v = b3[0];

    float lsum = 0.f;
    #pragma unroll
    for (int p = 0; p < 8; p++) {
        float s = 0.f;
        #pragma unroll
        for (int r = 0; r < 4; r++) {
            float h2 = fmaxf(acc[r][p] + bb2[r], 0.f);
            s += h2 * w3v[r];
        }
        // reduce over 64 lanes (output dim)
        for (int off = 32; off > 0; off >>= 1) s += __shfl_down(s, off);
        if (og == 0) {
            int t = 8 * w + p;
            int j = j0 + t;
            if (j > i && j < B) {
                float logit = s + b3v;
                float label = (j < MM) ? 1.f : 0.f;
                float bce = fmaxf(logit, 0.f) - logit * label +
                            log1pf(expf(-fabsf(logit)));
                lsum += bce;
            }
        }
    }
    if (og == 0) atomicAdd(bce_sum, lsum);
}

// ---------------- Kernel 5: combine ----------------
__global__ __launch_bounds__(128) void k_final(const float* __restrict__ logden,
                                               const float* __restrict__ slog,
                                               const float* __restrict__ bce_sum,
                                               float* __restrict__ out) {
    __shared__ float red[128];
    int t = threadIdx.x;
    float v = (float)(NN - 1 - t) * logden[t] - slog[t];
    red[t] = v;
    __syncthreads();
    for (int s = 64; s > 0; s >>= 1) {
        if (t < s) red[t] += red[t + s];
        __syncthreads();
    }
    if (t == 0) {
        float closs_sum = red[0];
        float closs = (-2.0f * (float)(NN - 1) / (float)NN) * closs_sum;
        float eloss = bce_sum[0] / (float)P_PAIRS;
        out[0] = closs + eloss;
    }
}

extern "C" void kernel_launch(void* const* d_in, const int* in_sizes, int n_in,
                              void* d_out, int out_size, void* d_ws, size_t ws_size,
                              hipStream_t stream) {
    const float* emb = (const float*)d_in[0];
    const float* W1  = (const float*)d_in[1];
    const float* b1  = (const float*)d_in[2];
    const float* W2  = (const float*)d_in[3];
    const float* b2  = (const float*)d_in[4];
    const float* W3  = (const float*)d_in[5];
    const float* b3  = (const float*)d_in[6];
    float* out = (float*)d_out;

    // Workspace layout (floats)
    float* ws = (float*)d_ws;
    float* z      = ws;                       // 512*768
    float* U      = z + B * D;                // 512*256
    float* V      = U + B * H;                // 512*256
    float* logden = V + B * H;                // 128
    float* slog   = logden + NN;              // 128
    float* bce    = slog + NN;                // 1

    hipMemsetAsync(bce, 0, sizeof(float), stream);

    k_normalize<<<B, 256, 0, stream>>>(emb, z);
    k_cstats<<<NN / 2, 256, 0, stream>>>(z, logden, slog);
    k_uv<<<B / 4, 256, 0, stream>>>(z, W1, U, V);
    k_pairs<<<dim3(16, NN), 256, 0, stream>>>(U, V, W2, b1, b2, W3, b3, bce);
    k_final<<<1, 128, 0, stream>>>(logden, slog, bce, out);
}

// Round 2
// 136.328 us; speedup vs baseline: 4.1259x; 4.1259x over previous
//
#include <hip/hip_runtime.h>
#include <hip/hip_bf16.h>
#include <math.h>

// Problem constants (B=512, D=768, H=256)
#define B 512
#define D 768
#define H 256
#define NN 128          // n = B/4
#define MM 256          // m = B/2
#define P_PAIRS 57280   // sum_{i=0}^{127} (511 - i)

typedef __attribute__((ext_vector_type(8))) __bf16 bf16x8;
typedef __attribute__((ext_vector_type(4))) __bf16 bf16x4;
typedef __attribute__((ext_vector_type(4))) float f32x4;

// MFMA 16x16x32 bf16 layouts (verified, learn_hip m89/m91/m120):
//   A[m = lane&15][k = (lane>>4)*8 + j]   (8 bf16 per lane, contiguous in k)
//   B[k = (lane>>4)*8 + j][n = lane&15]   -> load from [n][k] row-major, same as A
//   C/D: col = lane&15, row = (lane>>4)*4 + reg

// ---------------- Kernel 1: normalize rows -> zbf (bf16), + convert W2 -> bf16 ----------------
__global__ __launch_bounds__(256) void k_norm_conv(const float* __restrict__ emb,
                                                   const float* __restrict__ W2,
                                                   __bf16* __restrict__ zbf,
                                                   __bf16* __restrict__ W2b) {
    int bx = blockIdx.x;
    int t = threadIdx.x;
    if (bx < B) {
        // normalize row bx
        float4 v4 = make_float4(0.f, 0.f, 0.f, 0.f);
        float ss = 0.f;
        if (t < D / 4) {
            v4 = *(const float4*)(emb + bx * D + 4 * t);
            ss = v4.x * v4.x + v4.y * v4.y + v4.z * v4.z + v4.w * v4.w;
        }
        __shared__ float red[256];
        red[t] = ss;
        __syncthreads();
        for (int s = 128; s > 0; s >>= 1) {
            if (t < s) red[t] += red[t + s];
            __syncthreads();
        }
        float inv = 1.0f / fmaxf(sqrtf(red[0]), 1e-12f);
        if (t < D / 4) {
            bf16x4 o;
            o[0] = (__bf16)(v4.x * inv);
            o[1] = (__bf16)(v4.y * inv);
            o[2] = (__bf16)(v4.z * inv);
            o[3] = (__bf16)(v4.w * inv);
            *(bf16x4*)(zbf + bx * D + 4 * t) = o;
        }
    } else {
        // convert W2 (H*H = 65536 el) in float4 groups: 64 blocks x 256 threads
        int e4 = (bx - B) * 256 + t;     // 0 .. 16383
        float4 w = *(const float4*)(W2 + 4 * e4);
        bf16x4 o;
        o[0] = (__bf16)w.x; o[1] = (__bf16)w.y; o[2] = (__bf16)w.z; o[3] = (__bf16)w.w;
        *(bf16x4*)(W2b + 4 * e4) = o;
    }
}

// ---------------- Kernel 2: similarity stats via MFMA ----------------
// C[i][k] = dot(z_i, z_k); accumulate expsum[i] = sum_{k!=i} exp(2C), slog[i] = sum_{i<k<128} 2C
// grid (8 col-groups of 64, 8 row-groups of 16), 64 threads (1 wave)
__global__ __launch_bounds__(64) void k_sim(const __bf16* __restrict__ zbf,
                                            float* __restrict__ expsum,
                                            float* __restrict__ slog) {
    int m0 = blockIdx.y * 16;
    int n0 = blockIdx.x * 64;
    int lane = threadIdx.x;
    int r = lane & 15, q = lane >> 4;

    f32x4 acc[4] = {0};
    const __bf16* Ab = zbf + (m0 + r) * D + 8 * q;
    for (int s = 0; s < D / 32; s++) {
        bf16x8 a = *(const bf16x8*)(Ab + 32 * s);
        #pragma unroll
        for (int nt = 0; nt < 4; nt++) {
            bf16x8 b = *(const bf16x8*)(zbf + (n0 + 16 * nt + r) * D + 8 * q + 32 * s);
            acc[nt] = __builtin_amdgcn_mfma_f32_16x16x32_bf16(a, b, acc[nt], 0, 0, 0);
        }
    }

    #pragma unroll
    for (int rr = 0; rr < 4; rr++) {
        int irow = m0 + q * 4 + rr;
        float es = 0.f, sl = 0.f;
        #pragma unroll
        for (int nt = 0; nt < 4; nt++) {
            int kcol = n0 + nt * 16 + r;
            float C = acc[nt][rr];
            if (kcol != irow) es += expf(2.f * C);
            if (kcol > irow && kcol < NN) sl += 2.f * C;
        }
        #pragma unroll
        for (int m = 1; m <= 8; m <<= 1) {
            es += __shfl_xor(es, m);
            sl += __shfl_xor(sl, m);
        }
        if (r == 0) {
            atomicAdd(&expsum[irow], es);
            atomicAdd(&slog[irow], sl);
        }
    }
}

// ---------------- Kernel 3: U' = z@W1a^T + b1, V = z@W1b^T via MFMA ----------------
// Treat outputs as n in [0,512): n<256 -> U'[.,n], n>=256 -> V[.,n-256].
// Wstack row n (in [n][k] form) = W1[n&255][(n>>8)*768 + k]  (converted on the fly fp32->bf16)
// grid (8 col-groups of 64, 8 row-groups of 64), 128 threads (2 waves, 32 rows each)
__global__ __launch_bounds__(128) void k_uv(const __bf16* __restrict__ zbf,
                                            const float* __restrict__ W1,
                                            const float* __restrict__ b1,
                                            float* __restrict__ Up,
                                            float* __restrict__ Vv) {
    int w = threadIdx.x >> 6;
    int lane = threadIdx.x & 63;
    int r = lane & 15, q = lane >> 4;
    int m0 = blockIdx.y * 64 + w * 32;
    int n0 = blockIdx.x * 64;

    f32x4 acc[2][4] = {};
    const __bf16* Ab = zbf + (m0 + r) * D + 8 * q;

    // per-nt W1 row base (row-major over k)
    const float* wbase[4];
    #pragma unroll
    for (int nt = 0; nt < 4; nt++) {
        int n = n0 + 16 * nt + r;
        wbase[nt] = W1 + (n & 255) * (2 * D) + (n >> 8) * D + 8 * q;
    }

    for (int s = 0; s < D / 32; s++) {
        bf16x8 a0 = *(const bf16x8*)(Ab + 32 * s);
        bf16x8 a1 = *(const bf16x8*)(Ab + 16 * D + 32 * s);
        #pragma unroll
        for (int nt = 0; nt < 4; nt++) {
            f32x4 w0 = *(const f32x4*)(wbase[nt] + 32 * s);
            f32x4 w1 = *(const f32x4*)(wbase[nt] + 32 * s + 4);
            bf16x8 b;
            b[0] = (__bf16)w0[0]; b[1] = (__bf16)w0[1]; b[2] = (__bf16)w0[2]; b[3] = (__bf16)w0[3];
            b[4] = (__bf16)w1[0]; b[5] = (__bf16)w1[1]; b[6] = (__bf16)w1[2]; b[7] = (__bf16)w1[3];
            acc[0][nt] = __builtin_amdgcn_mfma_f32_16x16x32_bf16(a0, b, acc[0][nt], 0, 0, 0);
            acc[1][nt] = __builtin_amdgcn_mfma_f32_16x16x32_bf16(a1, b, acc[1][nt], 0, 0, 0);
        }
    }

    #pragma unroll
    for (int mt = 0; mt < 2; mt++) {
        #pragma unroll
        for (int nt = 0; nt < 4; nt++) {
            int n = n0 + 16 * nt + r;
            #pragma unroll
            for (int rr = 0; rr < 4; rr++) {
                int m = m0 + 16 * mt + 4 * q + rr;
                float C = acc[mt][nt][rr];
                if (n < H) Up[m * H + n] = C + b1[n];
                else       Vv[m * H + (n - H)] = C;
            }
        }
    }
}

// ---------------- Kernel 4: pair MLP via MFMA ----------------
// grid (8 j-tiles of 64, 128 i), 256 threads (4 waves; wave w -> cols 64w..64w+63, all 64 rows)
__global__ __launch_bounds__(256) void k_pairs(const float* __restrict__ Up,
                                               const float* __restrict__ Vv,
                                               const __bf16* __restrict__ W2b,
                                               const float* __restrict__ b2,
                                               const float* __restrict__ W3,
                                               const float* __restrict__ b3,
                                               float* __restrict__ bce_sum) {
    int i = blockIdx.y;
    int j0 = blockIdx.x * 64;
    if (j0 + 63 <= i) return;            // whole tile j <= i

    __shared__ __bf16 h1[64][264];       // padded to 264 (16B-aligned stride, 33.8 KB)
    __shared__ float redbuf[4][64];

    int tid = threadIdx.x;
    // ---- stage h1 = relu(U'[i] + V[j]) in bf16 ----
    int c = tid & 63;                    // h-quad id
    int r0 = tid >> 6;
    float4 u4 = *(const float4*)(Up + i * H + 4 * c);
    for (int it = 0; it < 16; it++) {
        int rj = r0 + 4 * it;
        float4 v4 = *(const float4*)(Vv + (j0 + rj) * H + 4 * c);
        bf16x4 hv;
        hv[0] = (__bf16)fmaxf(u4.x + v4.x, 0.f);
        hv[1] = (__bf16)fmaxf(u4.y + v4.y, 0.f);
        hv[2] = (__bf16)fmaxf(u4.z + v4.z, 0.f);
        hv[3] = (__bf16)fmaxf(u4.w + v4.w, 0.f);
        *(bf16x4*)&h1[rj][4 * c] = hv;
    }
    __syncthreads();

    // ---- 64x64 (per wave) MFMA: C = h1 @ W2^T ----
    int w = tid >> 6;
    int lane = tid & 63;
    int r = lane & 15, q = lane >> 4;

    f32x4 acc[4][4] = {};                // [mt][nt]
    #pragma unroll 2
    for (int s = 0; s < H / 32; s++) {
        bf16x8 a[4], bfr[4];
        #pragma unroll
        for (int mt = 0; mt < 4; mt++)
            a[mt] = *(const bf16x8*)&h1[16 * mt + r][32 * s + 8 * q];
        #pragma unroll
        for (int nt = 0; nt < 4; nt++)
            bfr[nt] = *(const bf16x8*)(W2b + (64 * w + 16 * nt + r) * H + 32 * s + 8 * q);
        #pragma unroll
        for (int mt = 0; mt < 4; mt++)
            #pragma unroll
            for (int nt = 0; nt < 4; nt++)
                acc[mt][nt] = __builtin_amdgcn_mfma_f32_16x16x32_bf16(a[mt], bfr[nt], acc[mt][nt], 0, 0, 0);
    }

    // ---- epilogue: h2 = relu(C + b2), partial logit = sum_n h2*W3 ----
    float part[4][4];                    // [mt][rr]
    #pragma unroll
    for (int mt = 0; mt < 4; mt++)
        #pragma unroll
        for (int rr = 0; rr < 4; rr++) part[mt][rr] = 0.f;

    #pragma unroll
    for (int nt = 0; nt < 4; nt++) {
        int n = 64 * w + 16 * nt + r;
        float b2v = b2[n], w3v = W3[n];
        #pragma unroll
        for (int mt = 0; mt < 4; mt++)
            #pragma unroll
            for (int rr = 0; rr < 4; rr++) {
                float h2 = fmaxf(acc[mt][nt][rr] + b2v, 0.f);
                part[mt][rr] += h2 * w3v;
            }
    }
    #pragma unroll
    for (int mt = 0; mt < 4; mt++)
        #pragma unroll
        for (int rr = 0; rr < 4; rr++) {
            float v = part[mt][rr];
            #pragma unroll
            for (int m = 1; m <= 8; m <<= 1) v += __shfl_xor(v, m);
            if (r == 0) redbuf[w][16 * mt + 4 * q + rr] = v;
        }
    __syncthreads();

    if (tid < 64) {
        int p = tid;
        int j = j0 + p;
        float lsum = 0.f;
        if (j > i) {
            float logit = redbuf[0][p] + redbuf[1][p] + redbuf[2][p] + redbuf[3][p] + b3[0];
            float label = (j < MM) ? 1.f : 0.f;
            lsum = fmaxf(logit, 0.f) - logit * label + log1pf(expf(-fabsf(logit)));
        }
        #pragma unroll
        for (int off = 32; off > 0; off >>= 1) lsum += __shfl_down(lsum, off);
        if (tid == 0) atomicAdd(bce_sum, lsum);
    }
}

// ---------------- Kernel 5: combine ----------------
__global__ __launch_bounds__(128) void k_final(const float* __restrict__ expsum,
                                               const float* __restrict__ slog,
                                               const float* __restrict__ bce_sum,
                                               float* __restrict__ out) {
    __shared__ float red[128];
    int t = threadIdx.x;
    red[t] = (float)(NN - 1 - t) * logf(expsum[t]) - slog[t];
    __syncthreads();
    for (int s = 64; s > 0; s >>= 1) {
        if (t < s) red[t] += red[t + s];
        __syncthreads();
    }
    if (t == 0) {
        float closs = (-2.0f * (float)(NN - 1) / (float)NN) * red[0];
        float eloss = bce_sum[0] / (float)P_PAIRS;
        out[0] = closs + eloss;
    }
}

extern "C" void kernel_launch(void* const* d_in, const int* in_sizes, int n_in,
                              void* d_out, int out_size, void* d_ws, size_t ws_size,
                              hipStream_t stream) {
    const float* emb = (const float*)d_in[0];
    const float* W1  = (const float*)d_in[1];
    const float* b1  = (const float*)d_in[2];
    const float* W2  = (const float*)d_in[3];
    const float* b2  = (const float*)d_in[4];
    const float* W3  = (const float*)d_in[5];
    const float* b3  = (const float*)d_in[6];
    float* out = (float*)d_out;

    // Workspace layout
    float* ws = (float*)d_ws;
    float* expsum = ws;                          // 128 f
    float* slog   = ws + 128;                    // 128 f
    float* bce    = ws + 256;                    // 1 f
    __bf16* zbf   = (__bf16*)(ws + 512);         // 512*768 bf16 = 768 KB
    __bf16* W2b   = zbf + B * D;                 // 256*256 bf16 = 128 KB
    float* Up     = (float*)(W2b + H * H);       // 512*256 f
    float* Vv     = Up + B * H;                  // 512*256 f

    hipMemsetAsync(expsum, 0, 257 * sizeof(float), stream);

    k_norm_conv<<<B + 64, 256, 0, stream>>>(emb, W2, zbf, W2b);
    k_sim<<<dim3(8, 8), 64, 0, stream>>>(zbf, expsum, slog);
    k_uv<<<dim3(8, 8), 128, 0, stream>>>(zbf, W1, b1, Up, Vv);
    k_pairs<<<dim3(8, NN), 256, 0, stream>>>(Up, Vv, W2b, b2, W3, b3, bce);
    k_final<<<1, 128, 0, stream>>>(expsum, slog, bce, out);
}